// Round 11
// baseline (7290.658 us; speedup 1.0000x reference)
//
#include <hip/hip_runtime.h>
#include <stdint.h>

typedef unsigned short u16;
typedef __bf16 bf16x8 __attribute__((ext_vector_type(8)));
typedef float  f32x4  __attribute__((ext_vector_type(4)));

#define GPTR(p) ((const __attribute__((address_space(1))) void*)(p))
#define LPTR(p) ((__attribute__((address_space(3))) void*)(p))

__device__ __forceinline__ u16 f2bf(float f) {
  uint32_t u = __float_as_uint(f);
  u += 0x7FFFu + ((u >> 16) & 1u);
  return (u16)(u >> 16);
}
__device__ __forceinline__ float bf2f(u16 h) {
  return __uint_as_float(((uint32_t)h) << 16);
}
__device__ __forceinline__ float sigf(float x) { return 1.0f / (1.0f + __expf(-x)); }
__device__ __forceinline__ float tanhf_(float x) { return 1.0f - 2.0f / (__expf(2.0f * x) + 1.0f); }

// ---------------- embedding gather ----------------
__global__ void k_emb(const int* __restrict__ seq, const float* __restrict__ wemb,
                      u16* __restrict__ x1) {
  const int row = blockIdx.x;          // 0..16383
  const int tok = seq[row];
  float4 v = ((const float4*)(wemb + (size_t)tok * 1024))[threadIdx.x];
  uint32_t lo = (uint32_t)f2bf(v.x) | ((uint32_t)f2bf(v.y) << 16);
  uint32_t hi = (uint32_t)f2bf(v.z) | ((uint32_t)f2bf(v.w) << 16);
  *(uint2*)(x1 + (size_t)row * 1024 + threadIdx.x * 4) = make_uint2(lo, hi);
}

// ---------------- marker index per row ----------------
__global__ void k_idx(const int* __restrict__ seq, int* __restrict__ idxb) {
  const int tid = threadIdx.x;         // 256
  const int b = tid >> 3, part = tid & 7;
  for (int t = part * 64; t < part * 64 + 64; ++t)
    if (seq[b * 512 + t] == 50000) idxb[b] = t;
}

// ---------------- cast 4096x1024 f32 -> bf16 ----------------
__global__ void k_cast(const float* __restrict__ src, u16* __restrict__ dst) {
  const int i = blockIdx.x * 256 + threadIdx.x;
  float4 v = ((const float4*)src)[i];
  uint32_t lo = (uint32_t)f2bf(v.x) | ((uint32_t)f2bf(v.y) << 16);
  uint32_t hi = (uint32_t)f2bf(v.z) | ((uint32_t)f2bf(v.w) << 16);
  *(uint2*)(dst + (size_t)i * 4) = make_uint2(lo, hi);
}

// ---------------- GEMM ----------------
// Output gx layout: [d][t][db(32)][col(16)][b(32)][q(4)] u16  (gates adjacent per lane).
// REMAP=0: A = x1 linear [m][1024].  REMAP=1: A = hstep layout [dir][s][db][row b][16].
template<int REMAP>
__global__ __launch_bounds__(256) void k_gemm(
    const u16* __restrict__ X, const u16* __restrict__ W,
    const float* __restrict__ bias, u16* __restrict__ gx)
{
  __shared__ u16 As[128][32];
  __shared__ u16 Bs[128][32];
  const int tid = threadIdx.x;
  const int lane = tid & 63;
  const int wv = tid >> 6;
  const int wm = wv >> 1, wn = wv & 1;
  const int bm = blockIdx.x, bn = blockIdx.y;
  const int srow = tid >> 2;
  const int scg = (tid & 3) * 8;
  const u16* Wb = W + (size_t)bn * 128 * 1024;
  f32x4 acc[4][4] = {};
  for (int k0 = 0; k0 < 1024; k0 += 32) {
    if constexpr (REMAP == 0) {
      const u16* Xb = X + (size_t)bm * 128 * 1024;
      __builtin_amdgcn_global_load_lds(GPTR(Xb + (size_t)srow * 1024 + k0 + scg),        LPTR(&As[srow][scg]),       16, 0, 0);
      __builtin_amdgcn_global_load_lds(GPTR(Xb + (size_t)(srow + 64) * 1024 + k0 + scg), LPTR(&As[srow + 64][scg]), 16, 0, 0);
    } else {
      const int b = bm >> 2;
      const int dirk = k0 >> 9;
      const int jj = (k0 & 511) + scg;
      const int t1 = (bm & 3) * 128 + srow;
      const int t2 = t1 + 64;
      const int s1 = dirk ? 511 - t1 : t1;
      const int s2 = dirk ? 511 - t2 : t2;
      const u16* src1 = X + (size_t)dirk * 8388608 + (size_t)s1 * 16384 + (jj >> 4) * 512 + b * 16 + (jj & 15);
      const u16* src2 = X + (size_t)dirk * 8388608 + (size_t)s2 * 16384 + (jj >> 4) * 512 + b * 16 + (jj & 15);
      __builtin_amdgcn_global_load_lds(GPTR(src1), LPTR(&As[srow][scg]),       16, 0, 0);
      __builtin_amdgcn_global_load_lds(GPTR(src2), LPTR(&As[srow + 64][scg]), 16, 0, 0);
    }
    __builtin_amdgcn_global_load_lds(GPTR(Wb + (size_t)srow * 1024 + k0 + scg),        LPTR(&Bs[srow][scg]),       16, 0, 0);
    __builtin_amdgcn_global_load_lds(GPTR(Wb + (size_t)(srow + 64) * 1024 + k0 + scg), LPTR(&Bs[srow + 64][scg]), 16, 0, 0);
    __syncthreads();
    const int kg = (lane >> 4) * 8;
    bf16x8 a4[4], b4[4];
    #pragma unroll
    for (int mt = 0; mt < 4; ++mt) a4[mt] = *(const bf16x8*)&As[wm * 64 + mt * 16 + (lane & 15)][kg];
    #pragma unroll
    for (int nt = 0; nt < 4; ++nt) b4[nt] = *(const bf16x8*)&Bs[wn * 64 + nt * 16 + (lane & 15)][kg];
    #pragma unroll
    for (int mt = 0; mt < 4; ++mt)
      #pragma unroll
      for (int nt = 0; nt < 4; ++nt)
        acc[mt][nt] = __builtin_amdgcn_mfma_f32_16x16x32_bf16(a4[mt], b4[nt], acc[mt][nt], 0, 0, 0);
    __syncthreads();
  }
  #pragma unroll
  for (int mt = 0; mt < 4; ++mt) {
    const int mbase = bm * 128 + wm * 64 + mt * 16 + ((lane >> 4) << 2);
    #pragma unroll
    for (int nt = 0; nt < 4; ++nt) {
      const int n = bn * 128 + wn * 64 + nt * 16 + (lane & 15);
      const float bi = bias[n];
      const int d = n >> 11;
      const int nn = n & 2047;
      const int q = nn >> 9;          // gate
      const int j = nn & 511;         // h column
      const int db2 = j >> 4, col = j & 15;
      #pragma unroll
      for (int r = 0; r < 4; ++r) {
        const int mm = mbase + r;
        const int b = mm >> 9, t = mm & 511;
        gx[(((size_t)(d * 512 + t) * 32 + db2) * 16 + col) * 128 + b * 4 + q] = f2bf(acc[mt][nt][r] + bi);
      }
    }
  }
}

// ---------------- persistent bidirectional recurrence, wave-autonomous ----------------
// 64 blocks x 128 thr (2 waves). dir = bid>>5, db = bid&31 owns h-cols [db*16,+16).
// Wave w owns batch rows [w*16, w*16+16) x all 4 gates -> cell fully in-register,
// ZERO barriers in the step loop. hstep: [dir][s][db][row][16] bf16, memset 0xFF
// (|h|<1 so a valid bf16 is never 0xFFFF; 2B-granular sentinel checks).
// Per step: probe rd1 (absorbs sync window) -> speculative bulk + probe rd2 -> masked
// sentinel backstop (terminating). ~2 LLC RTs/step.
__global__ __launch_bounds__(128, 1) void k_rec(
    const u16* __restrict__ gx, const float* __restrict__ whh, u16* hstep)
{
  const int bid = blockIdx.x;
  const int dir = bid >> 5;
  const int db = bid & 31;
  const int j0 = db * 16;
  const int tid = threadIdx.x;
  const int lane = tid & 63;
  const int w = tid >> 6;
  const int R = lane & 15;
  const int ks = lane >> 4;

  // ---- weights: bw[gate][kt], B-frag lane R = gate col j0+R
  bf16x8 bw[4][16];
  #pragma unroll
  for (int q = 0; q < 4; ++q) {
    const float* wp = whh + ((size_t)dir * 2048 + q * 512 + j0 + R) * 512 + ks * 8;
    #pragma unroll
    for (int kt = 0; kt < 16; ++kt) {
      float4 v0 = *(const float4*)(wp + kt * 32);
      float4 v1 = *(const float4*)(wp + kt * 32 + 4);
      union { u16 u[8]; bf16x8 v; } t;
      t.u[0] = f2bf(v0.x); t.u[1] = f2bf(v0.y); t.u[2] = f2bf(v0.z); t.u[3] = f2bf(v0.w);
      t.u[4] = f2bf(v1.x); t.u[5] = f2bf(v1.y); t.u[6] = f2bf(v1.z); t.u[7] = f2bf(v1.w);
      bw[q][kt] = t.v;
    }
  }

  const int rbase = w * 16 + ks * 4;              // first of this lane's 4 batch rows
  float c0 = 0.f, c1 = 0.f, c2 = 0.f, c3 = 0.f;
  const size_t dirbase = (size_t)dir * 8388608;
  // A-frag kt: chunk kt*2+(ks>>1), row w*16+R, col (ks&1)*8
  const u16* apbase = hstep + dirbase + (size_t)(ks >> 1) * 512 + (w * 16 + R) * 16 + (ks & 1) * 8;
  // probe: chunk lane&31, row w*16+15, cols 14-15 (last stores of producer wave w)
  const u16* prbase = hstep + dirbase + (size_t)(lane & 31) * 512 + (w * 16 + 15) * 16 + 14;
  // gx: [d][t][db][col][b][q]; lane col=R, rows rbase..+3
  const u16* gxbase = gx + (((size_t)dir * 16384 + (size_t)db) * 16 + R) * 128 + rbase * 4;

  uint2 gq0, gq1, gq2, gq3;
  {
    const int t0 = dir ? 511 : 0;
    const u16* g = gxbase + (size_t)t0 * 65536;
    gq0 = *(const uint2*)(g);     gq1 = *(const uint2*)(g + 4);
    gq2 = *(const uint2*)(g + 8); gq3 = *(const uint2*)(g + 12);
  }

  for (int s = 0; s < 512; ++s) {
    f32x4 acci = {0.f,0.f,0.f,0.f}, accf = {0.f,0.f,0.f,0.f};
    f32x4 accg = {0.f,0.f,0.f,0.f}, acco = {0.f,0.f,0.f,0.f};

    if (s) {
      const size_t slot = (size_t)(s - 1) * 16384;
      const u16* ap = apbase + slot;
      const u16* pp = prbase + slot;
      uint32_t fv;
      // probe round 1 (absorbs own-store ack + sync window)
      asm volatile("global_load_dword %0, %1, off sc0 sc1\n\ts_waitcnt vmcnt(0)"
                   : "=v"(fv) : "v"(pp) : "memory");
      const int pass1 = __all((int)(((fv & 0xFFFFu) != 0xFFFFu) & ((fv >> 16) != 0xFFFFu)));
      // speculative bulk (16 x dwordx4), concurrent with probe round 2+
      uint4 afu[16];
      #pragma unroll
      for (int kt = 0; kt < 16; ++kt)
        asm volatile("global_load_dwordx4 %0, %1, off sc0 sc1"
                     : "=v"(afu[kt]) : "v"(ap + kt * 1024) : "memory");
      if (!pass1) {
        while (true) {
          asm volatile("global_load_dword %0, %1, off sc0 sc1\n\ts_waitcnt vmcnt(0)"
                       : "=v"(fv) : "v"(pp) : "memory");
          if (__all((int)(((fv & 0xFFFFu) != 0xFFFFu) & ((fv >> 16) != 0xFFFFu)))) break;
        }
      } else {
        asm volatile("s_waitcnt vmcnt(0)" ::: "memory");
      }
      __builtin_amdgcn_sched_barrier(0);
      if (!pass1) {
        // masked sentinel backstop (bulk was speculative)
        while (true) {
          unsigned mask = 0;
          #pragma unroll
          for (int kt = 0; kt < 16; ++kt) {
            const uint4 xx = afu[kt];
            int ok = (int)(((xx.x & 0xFFFFu) != 0xFFFFu) & ((xx.x >> 16) != 0xFFFFu)
                         & ((xx.y & 0xFFFFu) != 0xFFFFu) & ((xx.y >> 16) != 0xFFFFu)
                         & ((xx.z & 0xFFFFu) != 0xFFFFu) & ((xx.z >> 16) != 0xFFFFu)
                         & ((xx.w & 0xFFFFu) != 0xFFFFu) & ((xx.w >> 16) != 0xFFFFu));
            if (!__all(ok)) mask |= 1u << kt;
          }
          if (!mask) break;
          #pragma unroll
          for (int kt = 0; kt < 16; ++kt)
            if (mask & (1u << kt))
              asm volatile("global_load_dwordx4 %0, %1, off sc0 sc1"
                           : "=v"(afu[kt]) : "v"(ap + kt * 1024) : "memory");
          asm volatile("s_waitcnt vmcnt(0)" ::: "memory");
          __builtin_amdgcn_sched_barrier(0);
        }
      }
      // MFMA: 4 independent gate chains
      #pragma unroll
      for (int kt = 0; kt < 16; ++kt) {
        bf16x8 a = __builtin_bit_cast(bf16x8, afu[kt]);
        acci = __builtin_amdgcn_mfma_f32_16x16x32_bf16(a, bw[0][kt], acci, 0, 0, 0);
        accf = __builtin_amdgcn_mfma_f32_16x16x32_bf16(a, bw[1][kt], accf, 0, 0, 0);
        accg = __builtin_amdgcn_mfma_f32_16x16x32_bf16(a, bw[2][kt], accg, 0, 0, 0);
        acco = __builtin_amdgcn_mfma_f32_16x16x32_bf16(a, bw[3][kt], acco, 0, 0, 0);
      }
    }

    // ---- in-register LSTM cell, 4 rows, no barrier
    u16* hb = hstep + dirbase + (size_t)s * 16384 + db * 512 + rbase * 16 + R;
#define CELL(RR, CC, GQ)                                                        \
    {                                                                           \
      float i = acci[RR] + bf2f((u16)(GQ.x & 0xFFFF));                          \
      float f = accf[RR] + bf2f((u16)(GQ.x >> 16));                             \
      float g = accg[RR] + bf2f((u16)(GQ.y & 0xFFFF));                          \
      float o = acco[RR] + bf2f((u16)(GQ.y >> 16));                             \
      CC = sigf(f) * CC + sigf(i) * tanhf_(g);                                  \
      uint32_t hv = (uint32_t)f2bf(sigf(o) * tanhf_(CC));                       \
      asm volatile("global_store_short %0, %1, off sc0 sc1"                     \
                   :: "v"(hb + RR * 16), "v"(hv) : "memory");                   \
    }
    CELL(0, c0, gq0)
    CELL(1, c1, gq1)
    CELL(2, c2, gq2)
    CELL(3, c3, gq3)
#undef CELL

    // ---- prefetch next-step gx (plain compiler-managed loads)
    if (s < 511) {
      const int tn = dir ? (511 - (s + 1)) : (s + 1);
      const u16* g = gxbase + (size_t)tn * 65536;
      gq0 = *(const uint2*)(g);     gq1 = *(const uint2*)(g + 4);
      gq2 = *(const uint2*)(g + 8); gq3 = *(const uint2*)(g + 12);
    }
  }
}

// ---------------- classifier stage 1 (reads hstep layout) ----------------
__global__ void k_cls1(const u16* __restrict__ hs, const int* __restrict__ idxb,
                       const float* __restrict__ w1, const float* __restrict__ b1,
                       float* __restrict__ h1) {
  __shared__ u16 hid[32][1024];
  const int tid = threadIdx.x;
  for (int g = tid; g < 2048; g += 256) {
    const int b = g >> 6;
    const int jc = g & 63;
    const int dir = jc >> 5;
    const int j16 = jc & 31;
    const int t = idxb[b];
    const int s = dir ? 511 - t : t;
    const u16* src = hs + (size_t)dir * 8388608 + (size_t)s * 16384 + j16 * 512 + b * 16;
    u16* dst = &hid[b][dir * 512 + j16 * 16];
    *(uint4*)(dst)     = *(const uint4*)(src);
    *(uint4*)(dst + 8) = *(const uint4*)(src + 8);
  }
  __syncthreads();
  for (int p = tid; p < 1024; p += 256) {
    const int j = blockIdx.x * 32 + (p >> 5);
    const int b = p & 31;
    const float4* wr = (const float4*)(w1 + (size_t)j * 1024);
    float s = 0.f;
    for (int k4 = 0; k4 < 256; ++k4) {
      float4 wv = wr[k4];
      const int k = k4 * 4;
      s += bf2f(hid[b][k]) * wv.x + bf2f(hid[b][k + 1]) * wv.y
         + bf2f(hid[b][k + 2]) * wv.z + bf2f(hid[b][k + 3]) * wv.w;
    }
    h1[b * 512 + j] = tanhf_(s + b1[j]);
  }
}

// ---------------- classifier stage 2: BCE-with-logits mean ----------------
__global__ void k_cls2(const float* __restrict__ h1, const float* __restrict__ w2,
                       const float* __restrict__ b2, const float* __restrict__ label,
                       float* __restrict__ out) {
  const int lane = threadIdx.x;   // 64
  float loss = 0.f;
  for (int b = 0; b < 32; ++b) {
    float s = 0.f;
    for (int k = lane; k < 512; k += 64) s += h1[b * 512 + k] * w2[k];
    for (int off = 32; off; off >>= 1) s += __shfl_down(s, off);
    if (lane == 0) {
      const float z = s + b2[0];
      const float y = label[b];
      const float sp = fmaxf(z, 0.f) + log1pf(__expf(-fabsf(z)));
      loss += sp - z * y;
    }
  }
  if (lane == 0) out[0] = loss / 32.0f;
}

extern "C" void kernel_launch(void* const* d_in, const int* in_sizes, int n_in,
                              void* d_out, int out_size, void* d_ws, size_t ws_size,
                              hipStream_t stream) {
  const int*   seq   = (const int*)  d_in[0];
  const float* label = (const float*)d_in[1];
  const float* wemb  = (const float*)d_in[2];
  const float* wih   = (const float*)d_in[3];
  const float* whh   = (const float*)d_in[4];
  const float* bb    = (const float*)d_in[5];
  const float* w1    = (const float*)d_in[6];
  const float* b1    = (const float*)d_in[7];
  const float* w2    = (const float*)d_in[8];
  const float* b2    = (const float*)d_in[9];

  u16* x1   = (u16*)d_ws;                       // [32][512][1024] bf16 (emb out; hstep layer2)
  u16* x2   = x1 + (size_t)16777216;            // hstep layer1 ([2][512][32][32][16])
  u16* gxb  = x2 + (size_t)16777216;            // [2][512][32][16][32][4] bf16
  u16* wb   = gxb + (size_t)67108864;           // [4096][1024] bf16
  float* h1 = (float*)(wb + 4194304);           // [32][512] f32
  int* idxb = (int*)(h1 + 16384);               // [32]

  // layer 1
  k_emb<<<16384, 256, 0, stream>>>(seq, wemb, x1);
  k_idx<<<1, 256, 0, stream>>>(seq, idxb);
  k_cast<<<4096, 256, 0, stream>>>(wih, wb);
  k_gemm<0><<<dim3(128, 32), 256, 0, stream>>>(x1, wb, bb, gxb);
  hipMemsetAsync(x2, 0xFF, (size_t)33554432, stream);      // hstep sentinel (layer1)
  k_rec<<<64, 128, 0, stream>>>(gxb, whh, x2);
  // layer 2
  k_cast<<<4096, 256, 0, stream>>>(wih + 4194304, wb);
  k_gemm<1><<<dim3(128, 32), 256, 0, stream>>>(x2, wb, bb + 4096, gxb);
  hipMemsetAsync(x1, 0xFF, (size_t)33554432, stream);      // hstep sentinel (layer2)
  k_rec<<<64, 128, 0, stream>>>(gxb, whh + 2097152, x1);
  // head
  k_cls1<<<16, 256, 0, stream>>>(x1, idxb, w1, b1, h1);
  k_cls2<<<1, 64, 0, stream>>>(h1, w2, b2, label, (float*)d_out);
}

// Round 12
// 5801.885 us; speedup vs baseline: 1.2566x; 1.2566x over previous
//
#include <hip/hip_runtime.h>
#include <stdint.h>

typedef unsigned short u16;
typedef __bf16 bf16x8 __attribute__((ext_vector_type(8)));
typedef float  f32x4  __attribute__((ext_vector_type(4)));

#define GPTR(p) ((const __attribute__((address_space(1))) void*)(p))
#define LPTR(p) ((__attribute__((address_space(3))) void*)(p))

__device__ __forceinline__ u16 f2bf(float f) {
  uint32_t u = __float_as_uint(f);
  u += 0x7FFFu + ((u >> 16) & 1u);
  return (u16)(u >> 16);
}
__device__ __forceinline__ float bf2f(u16 h) {
  return __uint_as_float(((uint32_t)h) << 16);
}
__device__ __forceinline__ float sigf(float x) { return 1.0f / (1.0f + __expf(-x)); }
__device__ __forceinline__ float tanhf_(float x) { return 1.0f - 2.0f / (__expf(2.0f * x) + 1.0f); }

// ---------------- embedding gather ----------------
__global__ void k_emb(const int* __restrict__ seq, const float* __restrict__ wemb,
                      u16* __restrict__ x1) {
  const int row = blockIdx.x;          // 0..16383
  const int tok = seq[row];
  float4 v = ((const float4*)(wemb + (size_t)tok * 1024))[threadIdx.x];
  uint32_t lo = (uint32_t)f2bf(v.x) | ((uint32_t)f2bf(v.y) << 16);
  uint32_t hi = (uint32_t)f2bf(v.z) | ((uint32_t)f2bf(v.w) << 16);
  *(uint2*)(x1 + (size_t)row * 1024 + threadIdx.x * 4) = make_uint2(lo, hi);
}

// ---------------- marker index per row ----------------
__global__ void k_idx(const int* __restrict__ seq, int* __restrict__ idxb) {
  const int tid = threadIdx.x;         // 256
  const int b = tid >> 3, part = tid & 7;
  for (int t = part * 64; t < part * 64 + 64; ++t)
    if (seq[b * 512 + t] == 50000) idxb[b] = t;
}

// ---------------- cast 4096x1024 f32 -> bf16 ----------------
__global__ void k_cast(const float* __restrict__ src, u16* __restrict__ dst) {
  const int i = blockIdx.x * 256 + threadIdx.x;
  float4 v = ((const float4*)src)[i];
  uint32_t lo = (uint32_t)f2bf(v.x) | ((uint32_t)f2bf(v.y) << 16);
  uint32_t hi = (uint32_t)f2bf(v.z) | ((uint32_t)f2bf(v.w) << 16);
  *(uint2*)(dst + (size_t)i * 4) = make_uint2(lo, hi);
}

// ---------------- GEMM: out layout [d][t][db(32)][col(16)][b(32)][q(4)] u16 ----------------
__global__ __launch_bounds__(256) void k_gemm(
    const u16* __restrict__ X, const u16* __restrict__ W,
    const float* __restrict__ bias, u16* __restrict__ gx)
{
  __shared__ u16 As[128][32];
  __shared__ u16 Bs[128][32];
  const int tid = threadIdx.x;
  const int lane = tid & 63;
  const int wv = tid >> 6;
  const int wm = wv >> 1, wn = wv & 1;
  const int bm = blockIdx.x, bn = blockIdx.y;
  const int srow = tid >> 2;
  const int scg = (tid & 3) * 8;
  const u16* Xb = X + (size_t)bm * 128 * 1024;
  const u16* Wb = W + (size_t)bn * 128 * 1024;
  f32x4 acc[4][4] = {};
  for (int k0 = 0; k0 < 1024; k0 += 32) {
    __builtin_amdgcn_global_load_lds(GPTR(Xb + (size_t)srow * 1024 + k0 + scg),        LPTR(&As[srow][scg]),       16, 0, 0);
    __builtin_amdgcn_global_load_lds(GPTR(Xb + (size_t)(srow + 64) * 1024 + k0 + scg), LPTR(&As[srow + 64][scg]), 16, 0, 0);
    __builtin_amdgcn_global_load_lds(GPTR(Wb + (size_t)srow * 1024 + k0 + scg),        LPTR(&Bs[srow][scg]),       16, 0, 0);
    __builtin_amdgcn_global_load_lds(GPTR(Wb + (size_t)(srow + 64) * 1024 + k0 + scg), LPTR(&Bs[srow + 64][scg]), 16, 0, 0);
    __syncthreads();
    const int kg = (lane >> 4) * 8;
    bf16x8 a4[4], b4[4];
    #pragma unroll
    for (int mt = 0; mt < 4; ++mt) a4[mt] = *(const bf16x8*)&As[wm * 64 + mt * 16 + (lane & 15)][kg];
    #pragma unroll
    for (int nt = 0; nt < 4; ++nt) b4[nt] = *(const bf16x8*)&Bs[wn * 64 + nt * 16 + (lane & 15)][kg];
    #pragma unroll
    for (int mt = 0; mt < 4; ++mt)
      #pragma unroll
      for (int nt = 0; nt < 4; ++nt)
        acc[mt][nt] = __builtin_amdgcn_mfma_f32_16x16x32_bf16(a4[mt], b4[nt], acc[mt][nt], 0, 0, 0);
    __syncthreads();
  }
  #pragma unroll
  for (int mt = 0; mt < 4; ++mt) {
    const int mbase = bm * 128 + wm * 64 + mt * 16 + ((lane >> 4) << 2);
    #pragma unroll
    for (int nt = 0; nt < 4; ++nt) {
      const int n = bn * 128 + wn * 64 + nt * 16 + (lane & 15);
      const float bi = bias[n];
      const int d = n >> 11;
      const int nn = n & 2047;
      const int q = nn >> 9;          // gate (i,f,g,o)
      const int j = nn & 511;         // h column
      const int db2 = j >> 4, col = j & 15;
      #pragma unroll
      for (int r = 0; r < 4; ++r) {
        const int mm = mbase + r;
        const int b = mm >> 9, t = mm & 511;
        gx[((((size_t)(d * 512 + t) * 32 + db2) * 16 + col) * 32 + b) * 4 + q] = f2bf(acc[mt][nt][r] + bi);
      }
    }
  }
}

// ---------------- persistent bidirectional recurrence, wave-autonomous + r8 protocol ----------------
// 64 blocks x 128 thr (2 waves). dir = bid>>5, db = bid&31 owns h-cols [db*16,+16).
// Wave w owns batch rows [w*16,+16) x all 4 gates -> LSTM cell fully in-register,
// ZERO barriers / ZERO LDS in the step loop.
// hstep: [dir][s][db][row 0..31][16] bf16, memset 0xFF (|h|<1 -> valid bf16 never 0xFFFF).
// Protocol (round-8 verbatim): probe spin (4B/lane fused load+vmcnt) -> bulk 16 x dwordx4
// staged vmcnt(8)/(0) under MFMA -> masked 2B-granular sentinel backstops (terminating).
__global__ __launch_bounds__(128, 1) void k_rec(
    const u16* __restrict__ gx, const float* __restrict__ whh,
    u16* __restrict__ xout, u16* hstep)
{
  const int bid = blockIdx.x;
  const int dir = bid >> 5;
  const int db = bid & 31;
  const int j0 = db * 16;
  const int tid = threadIdx.x;
  const int lane = tid & 63;
  const int w = tid >> 6;
  const int R = lane & 15;
  const int ks = lane >> 4;

  // ---- weights: bw[gate][kt], B-frag lane R = gate col j0+R
  bf16x8 bw[4][16];
  #pragma unroll
  for (int q = 0; q < 4; ++q) {
    const float* wp = whh + ((size_t)dir * 2048 + q * 512 + j0 + R) * 512 + ks * 8;
    #pragma unroll
    for (int kt = 0; kt < 16; ++kt) {
      float4 v0 = *(const float4*)(wp + kt * 32);
      float4 v1 = *(const float4*)(wp + kt * 32 + 4);
      union { u16 u[8]; bf16x8 v; } t;
      t.u[0] = f2bf(v0.x); t.u[1] = f2bf(v0.y); t.u[2] = f2bf(v0.z); t.u[3] = f2bf(v0.w);
      t.u[4] = f2bf(v1.x); t.u[5] = f2bf(v1.y); t.u[6] = f2bf(v1.z); t.u[7] = f2bf(v1.w);
      bw[q][kt] = t.v;
    }
  }

  const int rbase = w * 16 + ks * 4;              // first of this lane's 4 batch rows
  float c0 = 0.f, c1 = 0.f, c2 = 0.f, c3 = 0.f;
  const size_t dirbase = (size_t)dir * 8388608;   // dir * 512 * 16384
  // A-frag kt: chunk kt*2+(ks>>1), row w*16+R, col (ks&1)*8  (k = kt*32 + ks*8)
  const u16* apbase = hstep + dirbase + (size_t)(ks >> 1) * 512 + (w * 16 + R) * 16 + (ks & 1) * 8;
  // probe: producer (lane&31)'s row w*16+15, cols 14-15 (that wave's last cell store)
  const u16* prbase = hstep + dirbase + (size_t)(lane & 31) * 512 + (w * 16 + 15) * 16 + 14;
  // gx: [d][t][db][col][b][q]; lane col=R, rows rbase..+3 -> 32B contiguous
  const u16* gxbase = gx + (((size_t)dir * 16384 + (size_t)db) * 16 + R) * 128 + rbase * 4;

  uint2 gq0, gq1, gq2, gq3;
  {
    const int t0 = dir ? 511 : 0;
    const u16* g = gxbase + (size_t)t0 * 65536;
    gq0 = *(const uint2*)(g);     gq1 = *(const uint2*)(g + 4);
    gq2 = *(const uint2*)(g + 8); gq3 = *(const uint2*)(g + 12);
  }

#define VALID2(X) (int)((((X) & 0xFFFFu) != 0xFFFFu) & (((X) >> 16) != 0xFFFFu))

  for (int s = 0; s < 512; ++s) {
    const int tcur = dir ? (511 - s) : s;
    f32x4 acci = {0.f,0.f,0.f,0.f}, accf = {0.f,0.f,0.f,0.f};
    f32x4 accg = {0.f,0.f,0.f,0.f}, acco = {0.f,0.f,0.f,0.f};

    if (s) {
      const size_t slot = (size_t)(s - 1) * 16384;
      const u16* ap = apbase + slot;
      // ---- presence probe (round-8 verbatim): fused load+wait, spin until all valid
      {
        const u16* pp = prbase + slot;
        while (true) {
          uint32_t fv;
          asm volatile("global_load_dword %0, %1, off sc0 sc1\n\ts_waitcnt vmcnt(0)"
                       : "=v"(fv) : "v"(pp) : "memory");
          if (__all(VALID2(fv))) break;
        }
      }
      __builtin_amdgcn_sched_barrier(0);
      // ---- bulk A-fragment loads (16 x dwordx4, 2KB stride)
      uint4 afu[16];
      #pragma unroll
      for (int kt = 0; kt < 16; ++kt)
        asm volatile("global_load_dwordx4 %0, %1, off sc0 sc1"
                     : "=v"(afu[kt]) : "v"(ap + kt * 1024) : "memory");
      // ---- stage 1: frags 0..7
      asm volatile("s_waitcnt vmcnt(8)" ::: "memory");
      __builtin_amdgcn_sched_barrier(0);
      while (true) {   // backstop (rare)
        unsigned mask = 0;
        #pragma unroll
        for (int kt = 0; kt < 8; ++kt) {
          const uint4 xx = afu[kt];
          int ok = VALID2(xx.x) & VALID2(xx.y) & VALID2(xx.z) & VALID2(xx.w);
          if (!__all(ok)) mask |= 1u << kt;
        }
        if (!mask) break;
        #pragma unroll
        for (int kt = 0; kt < 8; ++kt)
          if (mask & (1u << kt))
            asm volatile("global_load_dwordx4 %0, %1, off sc0 sc1"
                         : "=v"(afu[kt]) : "v"(ap + kt * 1024) : "memory");
        asm volatile("s_waitcnt vmcnt(0)" ::: "memory");
        __builtin_amdgcn_sched_barrier(0);
      }
      #pragma unroll
      for (int kt = 0; kt < 8; ++kt) {
        bf16x8 a = __builtin_bit_cast(bf16x8, afu[kt]);
        acci = __builtin_amdgcn_mfma_f32_16x16x32_bf16(a, bw[0][kt], acci, 0, 0, 0);
        accf = __builtin_amdgcn_mfma_f32_16x16x32_bf16(a, bw[1][kt], accf, 0, 0, 0);
        accg = __builtin_amdgcn_mfma_f32_16x16x32_bf16(a, bw[2][kt], accg, 0, 0, 0);
        acco = __builtin_amdgcn_mfma_f32_16x16x32_bf16(a, bw[3][kt], acco, 0, 0, 0);
      }
      // ---- stage 2: frags 8..15
      asm volatile("s_waitcnt vmcnt(0)" ::: "memory");
      __builtin_amdgcn_sched_barrier(0);
      while (true) {   // backstop (rare)
        unsigned mask = 0;
        #pragma unroll
        for (int kt = 8; kt < 16; ++kt) {
          const uint4 xx = afu[kt];
          int ok = VALID2(xx.x) & VALID2(xx.y) & VALID2(xx.z) & VALID2(xx.w);
          if (!__all(ok)) mask |= 1u << (kt - 8);
        }
        if (!mask) break;
        #pragma unroll
        for (int kt = 8; kt < 16; ++kt)
          if (mask & (1u << (kt - 8)))
            asm volatile("global_load_dwordx4 %0, %1, off sc0 sc1"
                         : "=v"(afu[kt]) : "v"(ap + kt * 1024) : "memory");
        asm volatile("s_waitcnt vmcnt(0)" ::: "memory");
        __builtin_amdgcn_sched_barrier(0);
      }
      #pragma unroll
      for (int kt = 8; kt < 16; ++kt) {
        bf16x8 a = __builtin_bit_cast(bf16x8, afu[kt]);
        acci = __builtin_amdgcn_mfma_f32_16x16x32_bf16(a, bw[0][kt], acci, 0, 0, 0);
        accf = __builtin_amdgcn_mfma_f32_16x16x32_bf16(a, bw[1][kt], accf, 0, 0, 0);
        accg = __builtin_amdgcn_mfma_f32_16x16x32_bf16(a, bw[2][kt], accg, 0, 0, 0);
        acco = __builtin_amdgcn_mfma_f32_16x16x32_bf16(a, bw[3][kt], acco, 0, 0, 0);
      }
    }

    // ---- in-register LSTM cell, 4 rows, no barrier, no LDS
    u16* hb = hstep + dirbase + (size_t)s * 16384 + db * 512 + rbase * 16 + R;
    u16* xb = xout + ((size_t)rbase * 512 + tcur) * 1024 + dir * 512 + j0 + R;
#define CELL(RR, CC, GQ)                                                        \
    {                                                                           \
      float iv = acci[RR] + bf2f((u16)(GQ.x & 0xFFFF));                         \
      float fv_ = accf[RR] + bf2f((u16)(GQ.x >> 16));                           \
      float gv = accg[RR] + bf2f((u16)(GQ.y & 0xFFFF));                         \
      float ov = acco[RR] + bf2f((u16)(GQ.y >> 16));                            \
      CC = sigf(fv_) * CC + sigf(iv) * tanhf_(gv);                              \
      uint32_t hv = (uint32_t)f2bf(sigf(ov) * tanhf_(CC));                      \
      asm volatile("global_store_short %0, %1, off sc0 sc1"                     \
                   :: "v"(hb + RR * 16), "v"(hv) : "memory");                   \
      xb[(size_t)RR * 524288] = (u16)hv;                                        \
    }
    CELL(0, c0, gq0)
    CELL(1, c1, gq1)
    CELL(2, c2, gq2)
    CELL(3, c3, gq3)
#undef CELL

    // ---- prefetch next-step gx (plain compiler-managed loads, 32B contiguous)
    if (s < 511) {
      const int tn = dir ? (511 - (s + 1)) : (s + 1);
      const u16* g = gxbase + (size_t)tn * 65536;
      gq0 = *(const uint2*)(g);     gq1 = *(const uint2*)(g + 4);
      gq2 = *(const uint2*)(g + 8); gq3 = *(const uint2*)(g + 12);
    }
  }
#undef VALID2
}

// ---------------- classifier stage 1 ----------------
__global__ void k_cls1(const u16* __restrict__ x3, const int* __restrict__ idxb,
                       const float* __restrict__ w1, const float* __restrict__ b1,
                       float* __restrict__ h1) {
  __shared__ u16 hid[32][1024];
  const int tid = threadIdx.x;
  for (int g = tid; g < 4096; g += 256) {
    const int b = g >> 7;
    const int c8 = (g & 127) * 8;
    *(uint4*)&hid[b][c8] = *(const uint4*)(x3 + ((size_t)b * 512 + idxb[b]) * 1024 + c8);
  }
  __syncthreads();
  for (int p = tid; p < 1024; p += 256) {
    const int j = blockIdx.x * 32 + (p >> 5);
    const int b = p & 31;
    const float4* wr = (const float4*)(w1 + (size_t)j * 1024);
    float s = 0.f;
    for (int k4 = 0; k4 < 256; ++k4) {
      float4 wv = wr[k4];
      const int k = k4 * 4;
      s += bf2f(hid[b][k]) * wv.x + bf2f(hid[b][k + 1]) * wv.y
         + bf2f(hid[b][k + 2]) * wv.z + bf2f(hid[b][k + 3]) * wv.w;
    }
    h1[b * 512 + j] = tanhf_(s + b1[j]);
  }
}

// ---------------- classifier stage 2: BCE-with-logits mean ----------------
__global__ void k_cls2(const float* __restrict__ h1, const float* __restrict__ w2,
                       const float* __restrict__ b2, const float* __restrict__ label,
                       float* __restrict__ out) {
  const int lane = threadIdx.x;   // 64
  float loss = 0.f;
  for (int b = 0; b < 32; ++b) {
    float s = 0.f;
    for (int k = lane; k < 512; k += 64) s += h1[b * 512 + k] * w2[k];
    for (int off = 32; off; off >>= 1) s += __shfl_down(s, off);
    if (lane == 0) {
      const float z = s + b2[0];
      const float y = label[b];
      const float sp = fmaxf(z, 0.f) + log1pf(__expf(-fabsf(z)));
      loss += sp - z * y;
    }
  }
  if (lane == 0) out[0] = loss / 32.0f;
}

extern "C" void kernel_launch(void* const* d_in, const int* in_sizes, int n_in,
                              void* d_out, int out_size, void* d_ws, size_t ws_size,
                              hipStream_t stream) {
  const int*   seq   = (const int*)  d_in[0];
  const float* label = (const float*)d_in[1];
  const float* wemb  = (const float*)d_in[2];
  const float* wih   = (const float*)d_in[3];
  const float* whh   = (const float*)d_in[4];
  const float* bb    = (const float*)d_in[5];
  const float* w1    = (const float*)d_in[6];
  const float* b1    = (const float*)d_in[7];
  const float* w2    = (const float*)d_in[8];
  const float* b2    = (const float*)d_in[9];

  u16* x1   = (u16*)d_ws;                       // emb out / hstep layer1 / xout layer2
  u16* x2   = x1 + (size_t)16777216;            // xout layer1 / hstep layer2
  u16* gxb  = x2 + (size_t)16777216;            // [2][512][32][16][32][4] bf16
  u16* wb   = gxb + (size_t)67108864;           // [4096][1024] bf16
  float* h1 = (float*)(wb + 4194304);           // [32][512] f32
  int* idxb = (int*)(h1 + 16384);               // [32]

  // layer 1
  k_emb<<<16384, 256, 0, stream>>>(seq, wemb, x1);
  k_idx<<<1, 256, 0, stream>>>(seq, idxb);
  k_cast<<<4096, 256, 0, stream>>>(wih, wb);
  k_gemm<<<dim3(128, 32), 256, 0, stream>>>(x1, wb, bb, gxb);
  hipMemsetAsync(x1, 0xFF, (size_t)33554432, stream);      // hstep sentinel (layer1; emb dead)
  k_rec<<<64, 128, 0, stream>>>(gxb, whh, x2, x1);
  // layer 2
  k_cast<<<4096, 256, 0, stream>>>(wih + 4194304, wb);
  k_gemm<<<dim3(128, 32), 256, 0, stream>>>(x2, wb, bb + 4096, gxb);
  hipMemsetAsync(x2, 0xFF, (size_t)33554432, stream);      // hstep sentinel (layer2; x2 consumed)
  k_rec<<<64, 128, 0, stream>>>(gxb, whh + 2097152, x1, x2);
  // head
  k_cls1<<<16, 256, 0, stream>>>(x1, idxb, w1, b1, h1);
  k_cls2<<<1, 64, 0, stream>>>(h1, w2, b2, label, (float*)d_out);
}

// Round 13
// 4026.902 us; speedup vs baseline: 1.8105x; 1.4408x over previous
//
#include <hip/hip_runtime.h>
#include <stdint.h>

typedef unsigned short u16;
typedef __bf16 bf16x8 __attribute__((ext_vector_type(8)));
typedef float  f32x4  __attribute__((ext_vector_type(4)));

#define GPTR(p) ((const __attribute__((address_space(1))) void*)(p))
#define LPTR(p) ((__attribute__((address_space(3))) void*)(p))

__device__ __forceinline__ u16 f2bf(float f) {
  uint32_t u = __float_as_uint(f);
  u += 0x7FFFu + ((u >> 16) & 1u);
  return (u16)(u >> 16);
}
__device__ __forceinline__ float bf2f(u16 h) {
  return __uint_as_float(((uint32_t)h) << 16);
}
__device__ __forceinline__ float sigf(float x) { return 1.0f / (1.0f + __expf(-x)); }
__device__ __forceinline__ float tanhf_(float x) { return 1.0f - 2.0f / (__expf(2.0f * x) + 1.0f); }

// ---------------- embedding gather ----------------
__global__ void k_emb(const int* __restrict__ seq, const float* __restrict__ wemb,
                      u16* __restrict__ x1) {
  const int row = blockIdx.x;          // 0..16383
  const int tok = seq[row];
  float4 v = ((const float4*)(wemb + (size_t)tok * 1024))[threadIdx.x];
  uint32_t lo = (uint32_t)f2bf(v.x) | ((uint32_t)f2bf(v.y) << 16);
  uint32_t hi = (uint32_t)f2bf(v.z) | ((uint32_t)f2bf(v.w) << 16);
  *(uint2*)(x1 + (size_t)row * 1024 + threadIdx.x * 4) = make_uint2(lo, hi);
}

// ---------------- marker index per row ----------------
__global__ void k_idx(const int* __restrict__ seq, int* __restrict__ idxb) {
  const int tid = threadIdx.x;         // 256
  const int b = tid >> 3, part = tid & 7;
  for (int t = part * 64; t < part * 64 + 64; ++t)
    if (seq[b * 512 + t] == 50000) idxb[b] = t;
}

// ---------------- cast 4096x1024 f32 -> bf16 ----------------
__global__ void k_cast(const float* __restrict__ src, u16* __restrict__ dst) {
  const int i = blockIdx.x * 256 + threadIdx.x;
  float4 v = ((const float4*)src)[i];
  uint32_t lo = (uint32_t)f2bf(v.x) | ((uint32_t)f2bf(v.y) << 16);
  uint32_t hi = (uint32_t)f2bf(v.z) | ((uint32_t)f2bf(v.w) << 16);
  *(uint2*)(dst + (size_t)i * 4) = make_uint2(lo, hi);
}

// ---------------- GEMM: gx[d][t][b][(j>>4)*64 + q*16 + (j&15)] ----------------
__global__ __launch_bounds__(256) void k_gemm(
    const u16* __restrict__ X, const u16* __restrict__ W,
    const float* __restrict__ bias, u16* __restrict__ gx)
{
  __shared__ u16 As[128][32];
  __shared__ u16 Bs[128][32];
  const int tid = threadIdx.x;
  const int lane = tid & 63;
  const int wv = tid >> 6;
  const int wm = wv >> 1, wn = wv & 1;
  const int bm = blockIdx.x, bn = blockIdx.y;
  const int srow = tid >> 2;
  const int scg = (tid & 3) * 8;
  const u16* Xb = X + (size_t)bm * 128 * 1024;
  const u16* Wb = W + (size_t)bn * 128 * 1024;
  f32x4 acc[4][4] = {};
  for (int k0 = 0; k0 < 1024; k0 += 32) {
    __builtin_amdgcn_global_load_lds(GPTR(Xb + (size_t)srow * 1024 + k0 + scg),        LPTR(&As[srow][scg]),       16, 0, 0);
    __builtin_amdgcn_global_load_lds(GPTR(Xb + (size_t)(srow + 64) * 1024 + k0 + scg), LPTR(&As[srow + 64][scg]), 16, 0, 0);
    __builtin_amdgcn_global_load_lds(GPTR(Wb + (size_t)srow * 1024 + k0 + scg),        LPTR(&Bs[srow][scg]),       16, 0, 0);
    __builtin_amdgcn_global_load_lds(GPTR(Wb + (size_t)(srow + 64) * 1024 + k0 + scg), LPTR(&Bs[srow + 64][scg]), 16, 0, 0);
    __syncthreads();
    const int kg = (lane >> 4) * 8;
    bf16x8 a4[4], b4[4];
    #pragma unroll
    for (int mt = 0; mt < 4; ++mt) a4[mt] = *(const bf16x8*)&As[wm * 64 + mt * 16 + (lane & 15)][kg];
    #pragma unroll
    for (int nt = 0; nt < 4; ++nt) b4[nt] = *(const bf16x8*)&Bs[wn * 64 + nt * 16 + (lane & 15)][kg];
    #pragma unroll
    for (int mt = 0; mt < 4; ++mt)
      #pragma unroll
      for (int nt = 0; nt < 4; ++nt)
        acc[mt][nt] = __builtin_amdgcn_mfma_f32_16x16x32_bf16(a4[mt], b4[nt], acc[mt][nt], 0, 0, 0);
    __syncthreads();
  }
  #pragma unroll
  for (int mt = 0; mt < 4; ++mt) {
    const int mbase = bm * 128 + wm * 64 + mt * 16 + ((lane >> 4) << 2);
    #pragma unroll
    for (int nt = 0; nt < 4; ++nt) {
      const int n = bn * 128 + wn * 64 + nt * 16 + (lane & 15);
      const float bi = bias[n];
      const int d = n >> 11;
      const int nn = n & 2047;
      const int q = nn >> 9;          // gate
      const int j = nn & 511;         // h column
      const int col = (j >> 4) * 64 + q * 16 + (j & 15);
      #pragma unroll
      for (int r = 0; r < 4; ++r) {
        const int mm = mbase + r;
        const int b = mm >> 9, t = mm & 511;
        gx[((size_t)(d * 512 + t) * 32 + b) * 2048 + col] = f2bf(acc[mt][nt][r] + bi);
      }
    }
  }
}

// ---------------- persistent bidirectional recurrence (round-8 base + sleep-then-probe) ----------------
// 64 blocks: dir = bid>>5, db = bid&31 owns h-cols [db*16, db*16+16).
// hstep layout: [dir][slot s][producer db][row 0..31][16 cols] bf16 — producer stores
// ONE CONTIGUOUS 1KB chunk per step; consumer wave loads 2KB-strided 512B windows.
// Slots pre-memset 0xFF (|h|<1 so a valid pair is never 0xFFFFFFFF).
// NEW (single variable vs round 8): s_sleep(16) (~0.43us) before the probe spin so the
// first probe round arrives after producers' stores are LLC-visible (detect in 1 round).
__global__ __launch_bounds__(256, 1) void k_rec(
    const u16* __restrict__ gx, const float* __restrict__ whh,
    u16* __restrict__ xout, u16* hstep)
{
  const int bid = blockIdx.x;
  const int dir = bid >> 5;
  const int db = bid & 31;
  const int j0 = db * 16;
  const int tid = threadIdx.x;
  const int lane = tid & 63;
  const int wv = tid >> 6;
  const int mh = wv >> 1, nh = wv & 1;
  const int R = lane & 15;
  const int ks = lane >> 4;

  __shared__ float G[2][32][68];

  // ---- Whh chunk -> registers (bf16 B-fragments)
  bf16x8 bw[2][16];
  {
    #pragma unroll
    for (int nt = 0; nt < 2; ++nt) {
      const int q = nh * 2 + nt;   // gate: 0=i 1=f 2=g 3=o
      const float* wp = whh + ((size_t)dir * 2048 + q * 512 + j0 + R) * 512 + ks * 8;
      #pragma unroll
      for (int kt = 0; kt < 16; ++kt) {
        float4 v0 = *(const float4*)(wp + kt * 32);
        float4 v1 = *(const float4*)(wp + kt * 32 + 4);
        union { u16 u[8]; bf16x8 v; } t;
        t.u[0] = f2bf(v0.x); t.u[1] = f2bf(v0.y); t.u[2] = f2bf(v0.z); t.u[3] = f2bf(v0.w);
        t.u[4] = f2bf(v1.x); t.u[5] = f2bf(v1.y); t.u[6] = f2bf(v1.z); t.u[7] = f2bf(v1.w);
        bw[nt][kt] = t.v;
      }
    }
  }

  const int eb = tid >> 3;          // batch row for elementwise
  const int pr = (tid & 7) * 2;     // h-col pair within chunk
  float c0 = 0.f, c1 = 0.f;

  const size_t dirbase = (size_t)dir * 512 * 16384;
  // A-frag (kt): producer p = 2*kt + (ks>>1); addr = dirbase + slot + p*512 + row*16 + (ks&1)*8
  const u16* apbase = hstep + dirbase + (size_t)(ks >> 1) * 512 + (mh * 16 + R) * 16 + (ks & 1) * 8;
  // probe: one dword of producer (lane&31)'s chunk (row 31, cols 14-15)
  const u16* prbase = hstep + dirbase + (size_t)(lane & 31) * 512 + 510;
  const u16* gxeb   = gx + ((size_t)dir * 512 * 32 + eb) * 2048 + db * 64 + pr;

  uint32_t gq[4];
  {
    const int t0 = dir ? 511 : 0;
    const uint32_t* g0 = (const uint32_t*)(gxeb + (size_t)t0 * 65536);
    gq[0] = g0[0]; gq[1] = g0[8]; gq[2] = g0[16]; gq[3] = g0[24];
  }

  for (int s = 0; s < 512; ++s) {
    const int tcur = dir ? (511 - s) : s;
    const int gb = s & 1;
    f32x4 acc0 = {0.f,0.f,0.f,0.f}, acc1 = {0.f,0.f,0.f,0.f};

    if (s) {
      const size_t slot = (size_t)(s - 1) * 16384;
      const u16* ap = apbase + slot;
      // ---- sleep-then-probe: let producers' stores become LLC-visible, then detect in 1 round
      __builtin_amdgcn_s_sleep(16);
      {
        const u16* pp = prbase + slot;
        while (true) {
          uint32_t fv;
          asm volatile("global_load_dword %0, %1, off sc0 sc1\n\ts_waitcnt vmcnt(0)"
                       : "=v"(fv) : "v"(pp) : "memory");
          if (__all((int)(fv != 0xFFFFFFFFu))) break;
        }
      }
      __builtin_amdgcn_sched_barrier(0);
      // ---- bulk A-fragment loads (16 x dwordx4, 2KB stride)
      uint4 afu[16];
      #pragma unroll
      for (int kt = 0; kt < 16; ++kt)
        asm volatile("global_load_dwordx4 %0, %1, off sc0 sc1"
                     : "=v"(afu[kt]) : "v"(ap + kt * 1024) : "memory");
      // ---- stage 1: frags 0..7
      asm volatile("s_waitcnt vmcnt(8)" ::: "memory");
      __builtin_amdgcn_sched_barrier(0);
      while (true) {   // backstop (rare)
        unsigned mask = 0;
        #pragma unroll
        for (int kt = 0; kt < 8; ++kt) {
          int ok = (afu[kt].x != 0xFFFFFFFFu) && (afu[kt].y != 0xFFFFFFFFu) &&
                   (afu[kt].z != 0xFFFFFFFFu) && (afu[kt].w != 0xFFFFFFFFu);
          if (!__all(ok)) mask |= 1u << kt;
        }
        if (!mask) break;
        #pragma unroll
        for (int kt = 0; kt < 8; ++kt)
          if (mask & (1u << kt))
            asm volatile("global_load_dwordx4 %0, %1, off sc0 sc1"
                         : "=v"(afu[kt]) : "v"(ap + kt * 1024) : "memory");
        asm volatile("s_waitcnt vmcnt(0)" ::: "memory");
        __builtin_amdgcn_sched_barrier(0);
      }
      f32x4 a0 = {0.f,0.f,0.f,0.f}, a1 = {0.f,0.f,0.f,0.f};
      f32x4 b0 = {0.f,0.f,0.f,0.f}, b1 = {0.f,0.f,0.f,0.f};
      #pragma unroll
      for (int kt = 0; kt < 8; kt += 2) {
        bf16x8 x = __builtin_bit_cast(bf16x8, afu[kt]);
        bf16x8 y = __builtin_bit_cast(bf16x8, afu[kt + 1]);
        a0 = __builtin_amdgcn_mfma_f32_16x16x32_bf16(x, bw[0][kt],     a0, 0, 0, 0);
        a1 = __builtin_amdgcn_mfma_f32_16x16x32_bf16(x, bw[1][kt],     a1, 0, 0, 0);
        b0 = __builtin_amdgcn_mfma_f32_16x16x32_bf16(y, bw[0][kt + 1], b0, 0, 0, 0);
        b1 = __builtin_amdgcn_mfma_f32_16x16x32_bf16(y, bw[1][kt + 1], b1, 0, 0, 0);
      }
      // ---- stage 2: frags 8..15
      asm volatile("s_waitcnt vmcnt(0)" ::: "memory");
      __builtin_amdgcn_sched_barrier(0);
      while (true) {   // backstop (rare)
        unsigned mask = 0;
        #pragma unroll
        for (int kt = 8; kt < 16; ++kt) {
          int ok = (afu[kt].x != 0xFFFFFFFFu) && (afu[kt].y != 0xFFFFFFFFu) &&
                   (afu[kt].z != 0xFFFFFFFFu) && (afu[kt].w != 0xFFFFFFFFu);
          if (!__all(ok)) mask |= 1u << (kt - 8);
        }
        if (!mask) break;
        #pragma unroll
        for (int kt = 8; kt < 16; ++kt)
          if (mask & (1u << (kt - 8)))
            asm volatile("global_load_dwordx4 %0, %1, off sc0 sc1"
                         : "=v"(afu[kt]) : "v"(ap + kt * 1024) : "memory");
        asm volatile("s_waitcnt vmcnt(0)" ::: "memory");
        __builtin_amdgcn_sched_barrier(0);
      }
      #pragma unroll
      for (int kt = 8; kt < 16; kt += 2) {
        bf16x8 x = __builtin_bit_cast(bf16x8, afu[kt]);
        bf16x8 y = __builtin_bit_cast(bf16x8, afu[kt + 1]);
        a0 = __builtin_amdgcn_mfma_f32_16x16x32_bf16(x, bw[0][kt],     a0, 0, 0, 0);
        a1 = __builtin_amdgcn_mfma_f32_16x16x32_bf16(x, bw[1][kt],     a1, 0, 0, 0);
        b0 = __builtin_amdgcn_mfma_f32_16x16x32_bf16(y, bw[0][kt + 1], b0, 0, 0, 0);
        b1 = __builtin_amdgcn_mfma_f32_16x16x32_bf16(y, bw[1][kt + 1], b1, 0, 0, 0);
      }
      acc0 = a0 + b0;
      acc1 = a1 + b1;
    }

    #pragma unroll
    for (int r = 0; r < 4; ++r) {
      G[gb][mh * 16 + (lane >> 4) * 4 + r][nh * 32 + (lane & 15)]      = acc0[r];
      G[gb][mh * 16 + (lane >> 4) * 4 + r][nh * 32 + 16 + (lane & 15)] = acc1[r];
    }
    __syncthreads();                                   // G[gb] complete

    // ---- elementwise LSTM cell for (eb, j0+pr) and (eb, j0+pr+1)
    {
      float i0 = G[gb][eb][pr]      + bf2f((u16)(gq[0] & 0xFFFF));
      float i1 = G[gb][eb][pr + 1]  + bf2f((u16)(gq[0] >> 16));
      float f0 = G[gb][eb][pr + 16] + bf2f((u16)(gq[1] & 0xFFFF));
      float f1 = G[gb][eb][pr + 17] + bf2f((u16)(gq[1] >> 16));
      float g0 = G[gb][eb][pr + 32] + bf2f((u16)(gq[2] & 0xFFFF));
      float g1 = G[gb][eb][pr + 33] + bf2f((u16)(gq[2] >> 16));
      float o0 = G[gb][eb][pr + 48] + bf2f((u16)(gq[3] & 0xFFFF));
      float o1 = G[gb][eb][pr + 49] + bf2f((u16)(gq[3] >> 16));
      c0 = sigf(f0) * c0 + sigf(i0) * tanhf_(g0);
      c1 = sigf(f1) * c1 + sigf(i1) * tanhf_(g1);
      float h0 = sigf(o0) * tanhf_(c0);
      float h1 = sigf(o1) * tanhf_(c1);
      uint32_t hp = (uint32_t)f2bf(h0) | ((uint32_t)f2bf(h1) << 16);
      // contiguous 1KB producer chunk: [slot s][db][eb][pr]
      u16* hdst = hstep + dirbase + (size_t)s * 16384 + (size_t)db * 512 + eb * 16 + pr;
      asm volatile("global_store_dword %0, %1, off sc0 sc1"
                   :: "v"(hdst), "v"(hp) : "memory");
      *(uint32_t*)(xout + ((size_t)eb * 512 + tcur) * 1024 + dir * 512 + j0 + pr) = hp;
    }
    // ---- software-pipelined gx for next step (plain loads; drained by next poll's vmcnt(0))
    if (s < 511) {
      const int tn = dir ? (511 - (s + 1)) : (s + 1);
      const uint32_t* gn = (const uint32_t*)(gxeb + (size_t)tn * 65536);
      gq[0] = gn[0]; gq[1] = gn[8]; gq[2] = gn[16]; gq[3] = gn[24];
    }
    // no trailing barrier: G ping-pong, next step writes G[gb^1]
  }
}

// ---------------- classifier stage 1 ----------------
__global__ void k_cls1(const u16* __restrict__ x3, const int* __restrict__ idxb,
                       const float* __restrict__ w1, const float* __restrict__ b1,
                       float* __restrict__ h1) {
  __shared__ u16 hid[32][1024];
  const int tid = threadIdx.x;
  for (int g = tid; g < 4096; g += 256) {
    const int b = g >> 7;
    const int c8 = (g & 127) * 8;
    *(uint4*)&hid[b][c8] = *(const uint4*)(x3 + ((size_t)b * 512 + idxb[b]) * 1024 + c8);
  }
  __syncthreads();
  for (int p = tid; p < 1024; p += 256) {
    const int j = blockIdx.x * 32 + (p >> 5);
    const int b = p & 31;
    const float4* wr = (const float4*)(w1 + (size_t)j * 1024);
    float s = 0.f;
    for (int k4 = 0; k4 < 256; ++k4) {
      float4 wv = wr[k4];
      const int k = k4 * 4;
      s += bf2f(hid[b][k]) * wv.x + bf2f(hid[b][k + 1]) * wv.y
         + bf2f(hid[b][k + 2]) * wv.z + bf2f(hid[b][k + 3]) * wv.w;
    }
    h1[b * 512 + j] = tanhf_(s + b1[j]);
  }
}

// ---------------- classifier stage 2: BCE-with-logits mean ----------------
__global__ void k_cls2(const float* __restrict__ h1, const float* __restrict__ w2,
                       const float* __restrict__ b2, const float* __restrict__ label,
                       float* __restrict__ out) {
  const int lane = threadIdx.x;   // 64
  float loss = 0.f;
  for (int b = 0; b < 32; ++b) {
    float s = 0.f;
    for (int k = lane; k < 512; k += 64) s += h1[b * 512 + k] * w2[k];
    for (int off = 32; off; off >>= 1) s += __shfl_down(s, off);
    if (lane == 0) {
      const float z = s + b2[0];
      const float y = label[b];
      const float sp = fmaxf(z, 0.f) + log1pf(__expf(-fabsf(z)));
      loss += sp - z * y;
    }
  }
  if (lane == 0) out[0] = loss / 32.0f;
}

extern "C" void kernel_launch(void* const* d_in, const int* in_sizes, int n_in,
                              void* d_out, int out_size, void* d_ws, size_t ws_size,
                              hipStream_t stream) {
  const int*   seq   = (const int*)  d_in[0];
  const float* label = (const float*)d_in[1];
  const float* wemb  = (const float*)d_in[2];
  const float* wih   = (const float*)d_in[3];
  const float* whh   = (const float*)d_in[4];
  const float* bb    = (const float*)d_in[5];
  const float* w1    = (const float*)d_in[6];
  const float* b1    = (const float*)d_in[7];
  const float* w2    = (const float*)d_in[8];
  const float* b2    = (const float*)d_in[9];

  u16* x1   = (u16*)d_ws;                       // [32][512][1024] bf16 (hstep region for layer1)
  u16* x2   = x1 + (size_t)16777216;            // [32][512][1024] bf16 (hstep region for layer2)
  u16* gxb  = x2 + (size_t)16777216;            // [2][512][32][2048] bf16
  u16* wb   = gxb + (size_t)67108864;           // [4096][1024] bf16
  float* h1 = (float*)(wb + 4194304);           // [32][512] f32
  int* idxb = (int*)(h1 + 16384);               // [32]

  // layer 1
  k_emb<<<16384, 256, 0, stream>>>(seq, wemb, x1);
  k_idx<<<1, 256, 0, stream>>>(seq, idxb);
  k_cast<<<4096, 256, 0, stream>>>(wih, wb);
  k_gemm<<<dim3(128, 32), 256, 0, stream>>>(x1, wb, bb, gxb);
  hipMemsetAsync(x1, 0xFF, (size_t)33554432, stream);      // hstep sentinel (layer1)
  k_rec<<<64, 256, 0, stream>>>(gxb, whh, x2, x1);
  // layer 2
  k_cast<<<4096, 256, 0, stream>>>(wih + 4194304, wb);
  k_gemm<<<dim3(128, 32), 256, 0, stream>>>(x2, wb, bb + 4096, gxb);
  hipMemsetAsync(x2, 0xFF, (size_t)33554432, stream);      // hstep sentinel (layer2)
  k_rec<<<64, 256, 0, stream>>>(gxb, whh + 2097152, x1, x2);
  // head
  k_cls1<<<16, 256, 0, stream>>>(x1, idxb, w1, b1, h1);
  k_cls2<<<1, 64, 0, stream>>>(h1, w2, b2, label, (float*)d_out);
}